// Round 8
// baseline (285.480 us; speedup 1.0000x reference)
//
#include <hip/hip_runtime.h>
#include <hip/hip_bf16.h>
#include <math.h>

// KAN 2-layer forward, MI355X (gfx950) — round 8.
//   init_fused  : prep W1, prep W2, expand x -> F1, one launch
//   kan_gemm1   : F1 @ W1^T + exact-GELU -> h f32 (32MB). 128x128, BK=64,
//                 counted vmcnt, + setprio around MFMA cluster.
//   kan_gemm2   : expand(h) in-staging @ W2^T. r6-proven shape: BM=64, BN=256,
//                 BK=64, split-K=8, 4 blocks/CU, no atomic accumulation.
//                 NEW: last-block finisher sums the 8 partial slices (fixed
//                 z-order => deterministic) and writes out — reduce kernel gone.

typedef __attribute__((ext_vector_type(8))) short bf16x8;   // 8 x bf16
typedef __attribute__((ext_vector_type(4))) float f32x4;

#define TOKENS 8192
#define D_IN   256
#define D_HID  1024

// ---- exact uniform-cubic-B-spline features (closed form) ----
__device__ __forceinline__ void kan_features(float x, float f[8]) {
    f[0] = x * __builtin_amdgcn_rcpf(1.0f + __expf(-x));   // silu via v_rcp
    const float s = (x + 1.0f) * 1.5f + 3.0f;
    const float cf = floorf(s);
    const float u = s - cf;
    const int c = (int)cf;
    const float u2 = u * u, u3 = u2 * u;
    const float k6 = 1.0f / 6.0f;
    const float v3 = u3 * k6;
    const float v2 = (-3.0f * u3 + 3.0f * u2 + 3.0f * u + 1.0f) * k6;
    const float v1 = (3.0f * u3 - 6.0f * u2 + 4.0f) * k6;
    const float w1 = 1.0f - u;
    const float v0 = w1 * w1 * w1 * k6;
    const bool in = (s >= 0.0f) && (s < 9.0f);
#pragma unroll
    for (int j = 0; j < 6; ++j) {
        int d = c - j;
        float bv = (d == 0) ? v3 : (d == 1) ? v2 : (d == 2) ? v1 : (d == 3) ? v0 : 0.0f;
        f[1 + j] = in ? bv : 0.0f;
    }
    f[7] = 0.0f;
}

__device__ __forceinline__ void features_to_bf16(const float f[8], __hip_bfloat16 fb[8]) {
#pragma unroll
    for (int j = 0; j < 8; ++j) fb[j] = __float2bfloat16(f[j]);
}

// ---------------- fused init: expand_x (blocks 0..8191), prep W1, prep W2 ----------
__global__ void init_fused(const float* __restrict__ X, __hip_bfloat16* __restrict__ F,
                           const float* __restrict__ bw1, const float* __restrict__ sw1,
                           const float* __restrict__ sc1, __hip_bfloat16* __restrict__ W1,
                           const float* __restrict__ bw2, const float* __restrict__ sw2,
                           const float* __restrict__ sc2, __hip_bfloat16* __restrict__ W2) {
    const int b = blockIdx.x;
    if (b < 8192) {                          // expand x: 2M elements
        int idx = b * 256 + threadIdx.x;
        float f[8];
        kan_features(X[idx], f);
        __hip_bfloat16 fb[8];
        features_to_bf16(f, fb);
        *(bf16x8*)&F[(size_t)idx * 8] = *(bf16x8*)fb;
        return;
    }
    const bool w1 = (b < 9216);
    int idx = (w1 ? (b - 8192) : (b - 9216)) * 256 + threadIdx.x;   // < 262144
    const float* bw = w1 ? bw1 : bw2;
    const float* sw = w1 ? sw1 : sw2;
    const float* sc = w1 ? sc1 : sc2;
    __hip_bfloat16* Wo = w1 ? W1 : W2;
    float scl = sc[idx];
    __hip_bfloat16 row[8];
    row[0] = __float2bfloat16(bw[idx]);
#pragma unroll
    for (int j = 0; j < 6; ++j)
        row[1 + j] = __float2bfloat16(sw[idx * 6 + j] * scl);
    row[7] = __float2bfloat16(0.0f);
    *(bf16x8*)&Wo[(size_t)idx * 8] = *(bf16x8*)row;
}

#define GLL(src, dst) __builtin_amdgcn_global_load_lds(                         \
    (const __attribute__((address_space(1))) void*)(src),                       \
    (__attribute__((address_space(3))) void*)(dst), 16, 0, 0)

// ---------------- GEMM1: H = GELU(F1 @ W1^T), 128x128, BK=64, counted-vmcnt ----
__global__ __launch_bounds__(256, 2)
void kan_gemm1(const __hip_bfloat16* __restrict__ A,
               const __hip_bfloat16* __restrict__ W,
               float* __restrict__ H) {
    constexpr int K = D_IN * 8;            // 2048
    constexpr int NT = K / 64;             // 32 k-tiles
    __shared__ __hip_bfloat16 Al[2][128 * 64];
    __shared__ __hip_bfloat16 Bl[2][128 * 64];

    const int tid = threadIdx.x;
    const int wid = tid >> 6, lane = tid & 63;
    const int wm = wid >> 1, wn = wid & 1;
    const int lr = lane & 15, lg = lane >> 4;
    const int n0 = blockIdx.x * 128, o0 = blockIdx.y * 128;

    int srow[4], sslot[4];
#pragma unroll
    for (int p = 0; p < 4; ++p) {
        int item = tid + p * 256;
        srow[p] = item >> 3;
        sslot[p] = (item & 7) ^ (srow[p] & 7);
    }
    int aoff[2][4], boff[2][4];
#pragma unroll
    for (int ks = 0; ks < 2; ++ks)
#pragma unroll
        for (int f = 0; f < 4; ++f) {
            int ar = wm * 64 + f * 16 + lr;
            int br = wn * 64 + f * 16 + lr;
            aoff[ks][f] = ar * 64 + (((ks * 4 + lg) ^ (ar & 7)) * 8);
            boff[ks][f] = br * 64 + (((ks * 4 + lg) ^ (br & 7)) * 8);
        }

    f32x4 acc[4][4] = {};

#define STG1(buf, kt)                                                           \
    do {                                                                        \
        _Pragma("unroll")                                                       \
        for (int p = 0; p < 4; ++p) {                                           \
            GLL(A + (size_t)(n0 + srow[p]) * K + (kt) * 64 + sslot[p] * 8,      \
                &Al[buf][(tid + p * 256) * 8]);                                 \
            GLL(W + (size_t)(o0 + srow[p]) * K + (kt) * 64 + sslot[p] * 8,      \
                &Bl[buf][(tid + p * 256) * 8]);                                 \
        }                                                                       \
    } while (0)

    STG1(0, 0);
    STG1(1, 1);
    for (int t = 0; t < NT; ++t) {
        const int cur = t & 1;
        asm volatile("s_waitcnt vmcnt(8)" ::: "memory");
        __builtin_amdgcn_s_barrier();
        __builtin_amdgcn_sched_barrier(0);
        __builtin_amdgcn_s_setprio(1);
#pragma unroll
        for (int ks = 0; ks < 2; ++ks) {
            bf16x8 af[4], bfr[4];
#pragma unroll
            for (int f = 0; f < 4; ++f) af[f] = *(const bf16x8*)&Al[cur][aoff[ks][f]];
#pragma unroll
            for (int f = 0; f < 4; ++f) bfr[f] = *(const bf16x8*)&Bl[cur][boff[ks][f]];
#pragma unroll
            for (int fm = 0; fm < 4; ++fm)
#pragma unroll
                for (int fn = 0; fn < 4; ++fn)
                    acc[fm][fn] = __builtin_amdgcn_mfma_f32_16x16x32_bf16(
                        af[fm], bfr[fn], acc[fm][fn], 0, 0, 0);
        }
        __builtin_amdgcn_s_setprio(0);
        asm volatile("s_waitcnt lgkmcnt(0)" ::: "memory");
        __builtin_amdgcn_s_barrier();
        __builtin_amdgcn_sched_barrier(0);
        const int kn = (t + 2 < NT) ? t + 2 : NT - 1;
        STG1(cur, kn);
    }
#undef STG1
#pragma unroll
    for (int fm = 0; fm < 4; ++fm) {
#pragma unroll
        for (int fn = 0; fn < 4; ++fn) {
            int col = o0 + wn * 64 + fn * 16 + lr;
#pragma unroll
            for (int r = 0; r < 4; ++r) {
                int row = n0 + wm * 64 + fm * 16 + lg * 4 + r;
                float v = acc[fm][fn][r];
                H[(size_t)row * D_HID + col] = 0.5f * v * (1.0f + erff(v * 0.70710678118f));
            }
        }
    }
}

// ---------------- GEMM2 (r6 shape) + fused last-block reduction ----------------
// BM=64, BN=256, BK=64, split-K=8, 4 blocks/CU; partial stores; finisher sums.
__global__ __launch_bounds__(256, 4)
void kan_gemm2(const float* __restrict__ H,
               const __hip_bfloat16* __restrict__ W,
               float* __restrict__ P,
               float* __restrict__ out,
               unsigned* __restrict__ counters) {
    constexpr int OUT = D_IN, KD = D_HID * 8;   // 8192
    constexpr int NTT = KD / 64;                // 128 k-tiles
    __shared__ __hip_bfloat16 Al[64 * 64];      // 8KB
    __shared__ __hip_bfloat16 Bl[256 * 64];     // 32KB
    __shared__ unsigned done_ct;

    const int tid = threadIdx.x;
    const int wid = tid >> 6, lane = tid & 63;
    const int lr = lane & 15, lg = lane >> 4;
    const int n0 = blockIdx.x * 64;

    const int per = NTT / 8;                    // 16
    const int ks0 = blockIdx.z * per, ks1 = ks0 + per;

    int srow[8], sslot[8];
#pragma unroll
    for (int p = 0; p < 8; ++p) {
        int item = tid + p * 256;
        srow[p] = item >> 3;
        sslot[p] = (item & 7) ^ (srow[p] & 7);
    }
    const int ar0 = tid >> 3, ac = tid & 7;
    const float* hp0 = H + (size_t)(n0 + ar0) * D_HID + ac;
    const float* hp1 = H + (size_t)(n0 + ar0 + 32) * D_HID + ac;
    const int aw0 = ar0 * 64 + ((ac ^ (ar0 & 7)) * 8);
    const int aw1 = (ar0 + 32) * 64 + ((ac ^ (ar0 & 7)) * 8);

    int aoff[2][4], boff[2][4];
#pragma unroll
    for (int ks = 0; ks < 2; ++ks)
#pragma unroll
        for (int f = 0; f < 4; ++f) {
            int ar = f * 16 + lr;
            int br = wid * 64 + f * 16 + lr;
            aoff[ks][f] = ar * 64 + (((ks * 4 + lg) ^ (ar & 7)) * 8);
            boff[ks][f] = br * 64 + (((ks * 4 + lg) ^ (br & 7)) * 8);
        }

    f32x4 acc[4][4] = {};

    float hv0 = hp0[(size_t)ks0 * 8];
    float hv1 = hp1[(size_t)ks0 * 8];

    for (int kt = ks0; kt < ks1; ++kt) {
        float hc0 = hv0, hc1 = hv1;
        const int knext = (kt + 1 < ks1) ? kt + 1 : ks1 - 1;
        hv0 = hp0[(size_t)knext * 8];
        hv1 = hp1[(size_t)knext * 8];
        {
            float ff[8]; __hip_bfloat16 fb[8];
            kan_features(hc0, ff); features_to_bf16(ff, fb);
            *(bf16x8*)&Al[aw0] = *(bf16x8*)fb;
            kan_features(hc1, ff); features_to_bf16(ff, fb);
            *(bf16x8*)&Al[aw1] = *(bf16x8*)fb;
        }
#pragma unroll
        for (int p = 0; p < 8; ++p)
            GLL(W + (size_t)srow[p] * KD + (size_t)kt * 64 + sslot[p] * 8,
                &Bl[(tid + p * 256) * 8]);
        __syncthreads();
        __builtin_amdgcn_s_setprio(1);
#pragma unroll
        for (int ks = 0; ks < 2; ++ks) {
            bf16x8 af[4], bfr[4];
#pragma unroll
            for (int f = 0; f < 4; ++f) af[f] = *(const bf16x8*)&Al[aoff[ks][f]];
#pragma unroll
            for (int f = 0; f < 4; ++f) bfr[f] = *(const bf16x8*)&Bl[boff[ks][f]];
#pragma unroll
            for (int fm = 0; fm < 4; ++fm)
#pragma unroll
                for (int fn = 0; fn < 4; ++fn)
                    acc[fm][fn] = __builtin_amdgcn_mfma_f32_16x16x32_bf16(
                        af[fm], bfr[fn], acc[fm][fn], 0, 0, 0);
        }
        __builtin_amdgcn_s_setprio(0);
        __syncthreads();
    }

    // ---- epilogue: transpose via LDS (reuse Bl), coalesced f32x4 partial stores ----
    float* Pl = (float*)Bl;                      // 64 x 128 f32 = 32KB
    const size_t zoff = (size_t)blockIdx.z * TOKENS * OUT;
#pragma unroll
    for (int h = 0; h < 2; ++h) {
        __syncthreads();
        if ((wid >> 1) == h) {
#pragma unroll
            for (int fm = 0; fm < 4; ++fm)
#pragma unroll
                for (int fn = 0; fn < 4; ++fn) {
                    int c = (wid & 1) * 64 + fn * 16 + lr;
#pragma unroll
                    for (int r = 0; r < 4; ++r)
                        Pl[(fm * 16 + lg * 4 + r) * 128 + c] = acc[fm][fn][r];
                }
        }
        __syncthreads();
#pragma unroll
        for (int q = 0; q < 8; ++q) {
            int v = tid + q * 256;               // 0..2047
            int row = v >> 5, cv = (v & 31) * 4;
            *(f32x4*)&P[zoff + (size_t)(n0 + row) * OUT + h * 128 + cv] =
                *(const f32x4*)&Pl[row * 128 + cv];
        }
    }

    // ---- fused reduction: last arriving z-block for this x sums all 8 slices ----
    __threadfence();                             // make P stores visible device-wide
    __syncthreads();
    if (tid == 0) done_ct = atomicAdd(&counters[blockIdx.x], 1u);
    __syncthreads();
    if (done_ct == 7u) {                         // I'm the 8th: all slices stored
        __threadfence();                         // order: see others' P stores
        constexpr int NV = 64 * OUT / 4;         // 4096 f32x4 per x-block
#pragma unroll
        for (int p = 0; p < NV / 256; ++p) {
            int v = tid + p * 256;
            int row = v >> 6, cv = (v & 63) * 4;
            const size_t off = (size_t)(n0 + row) * OUT + cv;
            f32x4 s = *(const f32x4*)&P[off];    // z = 0
#pragma unroll
            for (int z = 1; z < 8; ++z)
                s += *(const f32x4*)&P[(size_t)z * TOKENS * OUT + off];
            *(f32x4*)&out[off] = s;              // fixed z-order: deterministic
        }
    }
}

extern "C" void kernel_launch(void* const* d_in, const int* in_sizes, int n_in,
                              void* d_out, int out_size, void* d_ws, size_t ws_size,
                              hipStream_t stream) {
    const float* x   = (const float*)d_in[0];
    const float* bw1 = (const float*)d_in[1];
    const float* sw1 = (const float*)d_in[2];
    const float* sc1 = (const float*)d_in[3];
    const float* bw2 = (const float*)d_in[4];
    const float* sw2 = (const float*)d_in[5];
    const float* sc2 = (const float*)d_in[6];
    float* out = (float*)d_out;

    char* ws = (char*)d_ws;
    __hip_bfloat16* W1 = (__hip_bfloat16*)ws;                   // 4MB
    __hip_bfloat16* W2 = (__hip_bfloat16*)(ws + (4ull << 20));  // 4MB
    __hip_bfloat16* F1 = (__hip_bfloat16*)(ws + (8ull << 20));  // 32MB
    float*          Hb = (float*)(ws + (40ull << 20));          // 32MB
    float*          Pp = (float*)(ws + (72ull << 20));          // 64MB
    unsigned*       ct = (unsigned*)(ws + (8ull << 20));        // reuse F1 head after gemm1

    if (ws_size < (136ull << 20)) return;

    // fused: expand_x (8192 blocks) + prep W1 (1024) + prep W2 (1024)
    init_fused<<<10240, 256, 0, stream>>>(x, F1, bw1, sw1, sc1, W1, bw2, sw2, sc2, W2);

    // GEMM1: (8192 x 2048) @ (1024 x 2048)^T + GELU -> Hb
    kan_gemm1<<<dim3(TOKENS / 128, D_HID / 128), 256, 0, stream>>>(F1, W1, Hb);

    // counters: 128 x-blocks, zeroed after gemm1 (F1 region is dead by then)
    hipMemsetAsync(ct, 0, 128 * sizeof(unsigned), stream);

    // GEMM2: expand(Hb) @ (256 x 8192)^T -> 8 partial slices + fused reduction
    kan_gemm2<<<dim3(TOKENS / 64, 1, 8), 256, 0, stream>>>(Hb, W2, Pp, out, ct);
}

// Round 9
// 163.700 us; speedup vs baseline: 1.7439x; 1.7439x over previous
//
#include <hip/hip_runtime.h>
#include <hip/hip_bf16.h>
#include <math.h>

// KAN 2-layer forward, MI355X (gfx950) — round 9.
//   init_fused   : prep W1, prep W2, expand x -> F1, one launch
//   kan_gemm1    : F1 @ W1^T + exact-GELU -> h f32 (32MB). 128x128, BK=64,
//                  counted vmcnt + setprio (r5/r8-proven, ~46us).
//   kan_gemm2    : expand(h) in-staging @ W2^T. BM=64, BN=128, BK=64,
//                  split-K=8 -> grid 2048, LDS 24KB -> 6 blocks/CU (r6 was 4).
//                  GLL issued BEFORE feature-VALU so loads overlap compute.
//                  No atomics, no device fences (r8 lesson: __threadfence on
//                  multi-XCD = L2 writeback per block = 2x HBM fetch).
//   reduce_split : sum 8 partial slices -> out (~13us, BW-bound).

typedef __attribute__((ext_vector_type(8))) short bf16x8;   // 8 x bf16
typedef __attribute__((ext_vector_type(4))) float f32x4;

#define TOKENS 8192
#define D_IN   256
#define D_HID  1024

// ---- exact uniform-cubic-B-spline features (closed form) ----
__device__ __forceinline__ void kan_features(float x, float f[8]) {
    f[0] = x * __builtin_amdgcn_rcpf(1.0f + __expf(-x));   // silu via v_rcp
    const float s = (x + 1.0f) * 1.5f + 3.0f;
    const float cf = floorf(s);
    const float u = s - cf;
    const int c = (int)cf;
    const float u2 = u * u, u3 = u2 * u;
    const float k6 = 1.0f / 6.0f;
    const float v3 = u3 * k6;
    const float v2 = (-3.0f * u3 + 3.0f * u2 + 3.0f * u + 1.0f) * k6;
    const float v1 = (3.0f * u3 - 6.0f * u2 + 4.0f) * k6;
    const float w1 = 1.0f - u;
    const float v0 = w1 * w1 * w1 * k6;
    const bool in = (s >= 0.0f) && (s < 9.0f);
#pragma unroll
    for (int j = 0; j < 6; ++j) {
        int d = c - j;
        float bv = (d == 0) ? v3 : (d == 1) ? v2 : (d == 2) ? v1 : (d == 3) ? v0 : 0.0f;
        f[1 + j] = in ? bv : 0.0f;
    }
    f[7] = 0.0f;
}

__device__ __forceinline__ void features_to_bf16(const float f[8], __hip_bfloat16 fb[8]) {
#pragma unroll
    for (int j = 0; j < 8; ++j) fb[j] = __float2bfloat16(f[j]);
}

// ---------------- fused init: expand_x (blocks 0..8191), prep W1, prep W2 ----------
__global__ void init_fused(const float* __restrict__ X, __hip_bfloat16* __restrict__ F,
                           const float* __restrict__ bw1, const float* __restrict__ sw1,
                           const float* __restrict__ sc1, __hip_bfloat16* __restrict__ W1,
                           const float* __restrict__ bw2, const float* __restrict__ sw2,
                           const float* __restrict__ sc2, __hip_bfloat16* __restrict__ W2) {
    const int b = blockIdx.x;
    if (b < 8192) {                          // expand x: 2M elements
        int idx = b * 256 + threadIdx.x;
        float f[8];
        kan_features(X[idx], f);
        __hip_bfloat16 fb[8];
        features_to_bf16(f, fb);
        *(bf16x8*)&F[(size_t)idx * 8] = *(bf16x8*)fb;
        return;
    }
    const bool w1 = (b < 9216);
    int idx = (w1 ? (b - 8192) : (b - 9216)) * 256 + threadIdx.x;   // < 262144
    const float* bw = w1 ? bw1 : bw2;
    const float* sw = w1 ? sw1 : sw2;
    const float* sc = w1 ? sc1 : sc2;
    __hip_bfloat16* Wo = w1 ? W1 : W2;
    float scl = sc[idx];
    __hip_bfloat16 row[8];
    row[0] = __float2bfloat16(bw[idx]);
#pragma unroll
    for (int j = 0; j < 6; ++j)
        row[1 + j] = __float2bfloat16(sw[idx * 6 + j] * scl);
    row[7] = __float2bfloat16(0.0f);
    *(bf16x8*)&Wo[(size_t)idx * 8] = *(bf16x8*)row;
}

#define GLL(src, dst) __builtin_amdgcn_global_load_lds(                         \
    (const __attribute__((address_space(1))) void*)(src),                       \
    (__attribute__((address_space(3))) void*)(dst), 16, 0, 0)

// ---------------- GEMM1: H = GELU(F1 @ W1^T), 128x128, BK=64, counted-vmcnt ----
__global__ __launch_bounds__(256, 2)
void kan_gemm1(const __hip_bfloat16* __restrict__ A,
               const __hip_bfloat16* __restrict__ W,
               float* __restrict__ H) {
    constexpr int K = D_IN * 8;            // 2048
    constexpr int NT = K / 64;             // 32 k-tiles
    __shared__ __hip_bfloat16 Al[2][128 * 64];
    __shared__ __hip_bfloat16 Bl[2][128 * 64];

    const int tid = threadIdx.x;
    const int wid = tid >> 6, lane = tid & 63;
    const int wm = wid >> 1, wn = wid & 1;
    const int lr = lane & 15, lg = lane >> 4;
    const int n0 = blockIdx.x * 128, o0 = blockIdx.y * 128;

    int srow[4], sslot[4];
#pragma unroll
    for (int p = 0; p < 4; ++p) {
        int item = tid + p * 256;
        srow[p] = item >> 3;
        sslot[p] = (item & 7) ^ (srow[p] & 7);
    }
    int aoff[2][4], boff[2][4];
#pragma unroll
    for (int ks = 0; ks < 2; ++ks)
#pragma unroll
        for (int f = 0; f < 4; ++f) {
            int ar = wm * 64 + f * 16 + lr;
            int br = wn * 64 + f * 16 + lr;
            aoff[ks][f] = ar * 64 + (((ks * 4 + lg) ^ (ar & 7)) * 8);
            boff[ks][f] = br * 64 + (((ks * 4 + lg) ^ (br & 7)) * 8);
        }

    f32x4 acc[4][4] = {};

#define STG1(buf, kt)                                                           \
    do {                                                                        \
        _Pragma("unroll")                                                       \
        for (int p = 0; p < 4; ++p) {                                           \
            GLL(A + (size_t)(n0 + srow[p]) * K + (kt) * 64 + sslot[p] * 8,      \
                &Al[buf][(tid + p * 256) * 8]);                                 \
            GLL(W + (size_t)(o0 + srow[p]) * K + (kt) * 64 + sslot[p] * 8,      \
                &Bl[buf][(tid + p * 256) * 8]);                                 \
        }                                                                       \
    } while (0)

    STG1(0, 0);
    STG1(1, 1);
    for (int t = 0; t < NT; ++t) {
        const int cur = t & 1;
        asm volatile("s_waitcnt vmcnt(8)" ::: "memory");
        __builtin_amdgcn_s_barrier();
        __builtin_amdgcn_sched_barrier(0);
        __builtin_amdgcn_s_setprio(1);
#pragma unroll
        for (int ks = 0; ks < 2; ++ks) {
            bf16x8 af[4], bfr[4];
#pragma unroll
            for (int f = 0; f < 4; ++f) af[f] = *(const bf16x8*)&Al[cur][aoff[ks][f]];
#pragma unroll
            for (int f = 0; f < 4; ++f) bfr[f] = *(const bf16x8*)&Bl[cur][boff[ks][f]];
#pragma unroll
            for (int fm = 0; fm < 4; ++fm)
#pragma unroll
                for (int fn = 0; fn < 4; ++fn)
                    acc[fm][fn] = __builtin_amdgcn_mfma_f32_16x16x32_bf16(
                        af[fm], bfr[fn], acc[fm][fn], 0, 0, 0);
        }
        __builtin_amdgcn_s_setprio(0);
        asm volatile("s_waitcnt lgkmcnt(0)" ::: "memory");
        __builtin_amdgcn_s_barrier();
        __builtin_amdgcn_sched_barrier(0);
        const int kn = (t + 2 < NT) ? t + 2 : NT - 1;
        STG1(cur, kn);
    }
#undef STG1
#pragma unroll
    for (int fm = 0; fm < 4; ++fm) {
#pragma unroll
        for (int fn = 0; fn < 4; ++fn) {
            int col = o0 + wn * 64 + fn * 16 + lr;
#pragma unroll
            for (int r = 0; r < 4; ++r) {
                int row = n0 + wm * 64 + fm * 16 + lg * 4 + r;
                float v = acc[fm][fn][r];
                H[(size_t)row * D_HID + col] = 0.5f * v * (1.0f + erff(v * 0.70710678118f));
            }
        }
    }
}

// ---------------- GEMM2: P[z] = expand(h) @ W2^T slice ----------------
// BM=64, BN=128, BK=64, split-K=8 -> grid 2048; LDS 24KB -> 6 blocks/CU.
__global__ __launch_bounds__(256, 6)
void kan_gemm2(const float* __restrict__ H,
               const __hip_bfloat16* __restrict__ W,
               float* __restrict__ P) {
    constexpr int OUT = D_IN, KD = D_HID * 8;   // 8192
    constexpr int NTT = KD / 64;                // 128 k-tiles
    __shared__ __hip_bfloat16 Al[64 * 64];      // 8KB
    __shared__ __hip_bfloat16 Bl[128 * 64];     // 16KB (reused as f32 in epi)

    const int tid = threadIdx.x;
    const int wid = tid >> 6, lane = tid & 63;
    const int wm = wid >> 1, wn = wid & 1;      // 2x2 waves: 32-row x 64-col tiles
    const int lr = lane & 15, lg = lane >> 4;
    const int n0 = blockIdx.x * 64;
    const int o0 = blockIdx.y * 128;

    const int per = NTT / 8;                    // 16
    const int ks0 = blockIdx.z * per, ks1 = ks0 + per;

    // B staging: 4 items/thread (128 rows x 8 slots), swizzled source slot
    int srow[4], sslot[4];
#pragma unroll
    for (int p = 0; p < 4; ++p) {
        int item = tid + p * 256;
        srow[p] = item >> 3;
        sslot[p] = (item & 7) ^ (srow[p] & 7);
    }
    // A features: 2 items/thread: rows r0, r0+32; h-col-in-tile = tid&7
    const int ar0 = tid >> 3, ac = tid & 7;
    const float* hp0 = H + (size_t)(n0 + ar0) * D_HID + ac;
    const float* hp1 = H + (size_t)(n0 + ar0 + 32) * D_HID + ac;
    const int aw0 = ar0 * 64 + ((ac ^ (ar0 & 7)) * 8);
    const int aw1 = (ar0 + 32) * 64 + ((ac ^ ((ar0 + 32) & 7)) * 8);

    int aoff[2][2], boff[2][4];
#pragma unroll
    for (int ks = 0; ks < 2; ++ks) {
#pragma unroll
        for (int f = 0; f < 2; ++f) {
            int ar = wm * 32 + f * 16 + lr;
            aoff[ks][f] = ar * 64 + (((ks * 4 + lg) ^ (ar & 7)) * 8);
        }
#pragma unroll
        for (int f = 0; f < 4; ++f) {
            int br = wn * 64 + f * 16 + lr;
            boff[ks][f] = br * 64 + (((ks * 4 + lg) ^ (br & 7)) * 8);
        }
    }

    f32x4 acc[2][4] = {};

    float hv0 = hp0[(size_t)ks0 * 8];
    float hv1 = hp1[(size_t)ks0 * 8];

    for (int kt = ks0; kt < ks1; ++kt) {
        // B: issue loads FIRST so feature-VALU overlaps their latency
#pragma unroll
        for (int p = 0; p < 4; ++p)
            GLL(W + (size_t)(o0 + srow[p]) * KD + (size_t)kt * 64 + sslot[p] * 8,
                &Bl[(tid + p * 256) * 8]);
        float hc0 = hv0, hc1 = hv1;
        const int knext = (kt + 1 < ks1) ? kt + 1 : ks1 - 1;
        hv0 = hp0[(size_t)knext * 8];
        hv1 = hp1[(size_t)knext * 8];
        {
            float ff[8]; __hip_bfloat16 fb[8];
            kan_features(hc0, ff); features_to_bf16(ff, fb);
            *(bf16x8*)&Al[aw0] = *(bf16x8*)fb;
            kan_features(hc1, ff); features_to_bf16(ff, fb);
            *(bf16x8*)&Al[aw1] = *(bf16x8*)fb;
        }
        __syncthreads();
#pragma unroll
        for (int ks = 0; ks < 2; ++ks) {
            bf16x8 af[2], bfr[4];
#pragma unroll
            for (int f = 0; f < 2; ++f) af[f] = *(const bf16x8*)&Al[aoff[ks][f]];
#pragma unroll
            for (int f = 0; f < 4; ++f) bfr[f] = *(const bf16x8*)&Bl[boff[ks][f]];
#pragma unroll
            for (int fm = 0; fm < 2; ++fm)
#pragma unroll
                for (int fn = 0; fn < 4; ++fn)
                    acc[fm][fn] = __builtin_amdgcn_mfma_f32_16x16x32_bf16(
                        af[fm], bfr[fn], acc[fm][fn], 0, 0, 0);
        }
        __syncthreads();
    }

    // ---- epilogue: transpose via LDS (reuse Bl as 64x64 f32), coalesced stores ----
    float* Pl = (float*)Bl;                      // 64 x 64 f32 = 16KB
    const size_t zoff = (size_t)blockIdx.z * TOKENS * OUT;
#pragma unroll
    for (int h = 0; h < 2; ++h) {                // col-half h: waves with wn==h
        __syncthreads();
        if (wn == h) {
#pragma unroll
            for (int fm = 0; fm < 2; ++fm)
#pragma unroll
                for (int fn = 0; fn < 4; ++fn)
#pragma unroll
                    for (int r = 0; r < 4; ++r)
                        Pl[(wm * 32 + fm * 16 + lg * 4 + r) * 64 + fn * 16 + lr] =
                            acc[fm][fn][r];
        }
        __syncthreads();
#pragma unroll
        for (int p = 0; p < 4; ++p) {
            int v = tid + p * 256;               // 0..1023
            int row = v >> 4, cv = (v & 15) * 4;
            *(f32x4*)&P[zoff + (size_t)(n0 + row) * OUT + o0 + h * 64 + cv] =
                *(const f32x4*)&Pl[row * 64 + cv];
        }
    }
}

// ---------------- reduce 8 partial slices -> out ----------------
__global__ void reduce_split(const float* __restrict__ P, float* __restrict__ out,
                             int nvec) {
    int i = blockIdx.x * 256 + threadIdx.x;
    if (i >= nvec) return;
    const f32x4* Pv = (const f32x4*)P;
    f32x4 s = Pv[i];
#pragma unroll
    for (int z = 1; z < 8; ++z) s += Pv[(size_t)z * nvec + i];
    ((f32x4*)out)[i] = s;
}

extern "C" void kernel_launch(void* const* d_in, const int* in_sizes, int n_in,
                              void* d_out, int out_size, void* d_ws, size_t ws_size,
                              hipStream_t stream) {
    const float* x   = (const float*)d_in[0];
    const float* bw1 = (const float*)d_in[1];
    const float* sw1 = (const float*)d_in[2];
    const float* sc1 = (const float*)d_in[3];
    const float* bw2 = (const float*)d_in[4];
    const float* sw2 = (const float*)d_in[5];
    const float* sc2 = (const float*)d_in[6];
    float* out = (float*)d_out;

    char* ws = (char*)d_ws;
    __hip_bfloat16* W1 = (__hip_bfloat16*)ws;                   // 4MB
    __hip_bfloat16* W2 = (__hip_bfloat16*)(ws + (4ull << 20));  // 4MB
    __hip_bfloat16* F1 = (__hip_bfloat16*)(ws + (8ull << 20));  // 32MB
    float*          Hb = (float*)(ws + (40ull << 20));          // 32MB
    float*          Pp = (float*)(ws + (72ull << 20));          // 64MB

    if (ws_size < (136ull << 20)) return;

    // fused: expand_x (8192 blocks) + prep W1 (1024) + prep W2 (1024)
    init_fused<<<10240, 256, 0, stream>>>(x, F1, bw1, sw1, sc1, W1, bw2, sw2, sc2, W2);

    // GEMM1: (8192 x 2048) @ (1024 x 2048)^T + GELU -> Hb
    kan_gemm1<<<dim3(TOKENS / 128, D_HID / 128), 256, 0, stream>>>(F1, W1, Hb);

    // GEMM2: expand(Hb) @ (256 x 8192)^T -> 8 partial slices
    kan_gemm2<<<dim3(TOKENS / 64, 2, 8), 256, 0, stream>>>(Hb, W2, Pp);

    // Reduce partials -> out
    const int nvec = TOKENS * D_IN / 4;  // 524288
    reduce_split<<<(nvec + 255) / 256, 256, 0, stream>>>(Pp, out, nvec);
}

// Round 10
// 148.141 us; speedup vs baseline: 1.9271x; 1.1050x over previous
//
#include <hip/hip_runtime.h>
#include <hip/hip_bf16.h>
#include <math.h>

// KAN 2-layer forward, MI355X (gfx950) — round 10.
//   init_fused   : prep W1 (row-major aug), prep W2 -> W2f FRAGMENT-MAJOR
//                  (W2f[k/32][col][k%32], so MFMA B-frags are 1KB-contiguous
//                  coalesced register loads), expand x -> F1.
//   kan_gemm1    : unchanged r5/r8 (128x128, BK=64, counted vmcnt, setprio).
//   kan_gemm2    : BM=64, BN=256, BK=64, split-K=8 (r6 shape) but B streamed
//                  GLOBAL->REGISTERS (no B LDS, no vmcnt drain at barriers).
//                  Only A (features) in LDS, dbuf, 2 raw s_barrier + lgkmcnt.
//   reduce_split : sum 8 partial slices -> out.
// r8 lesson kept: no device fences / atomics in hot kernels.

typedef __attribute__((ext_vector_type(8))) short bf16x8;   // 8 x bf16
typedef __attribute__((ext_vector_type(4))) float f32x4;

#define TOKENS 8192
#define D_IN   256
#define D_HID  1024

// ---- exact uniform-cubic-B-spline features (closed form) ----
__device__ __forceinline__ void kan_features(float x, float f[8]) {
    f[0] = x * __builtin_amdgcn_rcpf(1.0f + __expf(-x));   // silu via v_rcp
    const float s = (x + 1.0f) * 1.5f + 3.0f;
    const float cf = floorf(s);
    const float u = s - cf;
    const int c = (int)cf;
    const float u2 = u * u, u3 = u2 * u;
    const float k6 = 1.0f / 6.0f;
    const float v3 = u3 * k6;
    const float v2 = (-3.0f * u3 + 3.0f * u2 + 3.0f * u + 1.0f) * k6;
    const float v1 = (3.0f * u3 - 6.0f * u2 + 4.0f) * k6;
    const float w1 = 1.0f - u;
    const float v0 = w1 * w1 * w1 * k6;
    const bool in = (s >= 0.0f) && (s < 9.0f);
#pragma unroll
    for (int j = 0; j < 6; ++j) {
        int d = c - j;
        float bv = (d == 0) ? v3 : (d == 1) ? v2 : (d == 2) ? v1 : (d == 3) ? v0 : 0.0f;
        f[1 + j] = in ? bv : 0.0f;
    }
    f[7] = 0.0f;
}

__device__ __forceinline__ void features_to_bf16(const float f[8], __hip_bfloat16 fb[8]) {
#pragma unroll
    for (int j = 0; j < 8; ++j) fb[j] = __float2bfloat16(f[j]);
}

// ---------------- fused init ----------------
// blocks 0..8191: expand x. 8192..9215: W1 (row-major). 9216..10239: W2 -> W2f.
__global__ void init_fused(const float* __restrict__ X, __hip_bfloat16* __restrict__ F,
                           const float* __restrict__ bw1, const float* __restrict__ sw1,
                           const float* __restrict__ sc1, __hip_bfloat16* __restrict__ W1,
                           const float* __restrict__ bw2, const float* __restrict__ sw2,
                           const float* __restrict__ sc2, __hip_bfloat16* __restrict__ W2f) {
    const int b = blockIdx.x;
    if (b < 8192) {                          // expand x: 2M elements
        int idx = b * 256 + threadIdx.x;
        float f[8];
        kan_features(X[idx], f);
        __hip_bfloat16 fb[8];
        features_to_bf16(f, fb);
        *(bf16x8*)&F[(size_t)idx * 8] = *(bf16x8*)fb;
        return;
    }
    const bool w1 = (b < 9216);
    int idx = (w1 ? (b - 8192) : (b - 9216)) * 256 + threadIdx.x;   // < 262144
    const float* bw = w1 ? bw1 : bw2;
    const float* sw = w1 ? sw1 : sw2;
    const float* sc = w1 ? sc1 : sc2;
    float scl = sc[idx];
    __hip_bfloat16 row[8];
    row[0] = __float2bfloat16(bw[idx]);
#pragma unroll
    for (int j = 0; j < 6; ++j)
        row[1 + j] = __float2bfloat16(sw[idx * 6 + j] * scl);
    row[7] = __float2bfloat16(0.0f);
    if (w1) {
        *(bf16x8*)&W1[(size_t)idx * 8] = *(bf16x8*)row;          // row-major aug
    } else {
        // fragment-major: elem (o, k=i*8+j) -> W2f[(k>>5)*8192 + o*32 + (k&31)]
        int o = idx >> 10, i = idx & 1023;
        *(bf16x8*)&W2f[(size_t)(i >> 2) * 8192 + o * 32 + (i & 3) * 8] = *(bf16x8*)row;
    }
}

#define GLL(src, dst) __builtin_amdgcn_global_load_lds(                         \
    (const __attribute__((address_space(1))) void*)(src),                       \
    (__attribute__((address_space(3))) void*)(dst), 16, 0, 0)

// ---------------- GEMM1: H = GELU(F1 @ W1^T), 128x128, BK=64, counted-vmcnt ----
__global__ __launch_bounds__(256, 2)
void kan_gemm1(const __hip_bfloat16* __restrict__ A,
               const __hip_bfloat16* __restrict__ W,
               float* __restrict__ H) {
    constexpr int K = D_IN * 8;            // 2048
    constexpr int NT = K / 64;             // 32 k-tiles
    __shared__ __hip_bfloat16 Al[2][128 * 64];
    __shared__ __hip_bfloat16 Bl[2][128 * 64];

    const int tid = threadIdx.x;
    const int wid = tid >> 6, lane = tid & 63;
    const int wm = wid >> 1, wn = wid & 1;
    const int lr = lane & 15, lg = lane >> 4;
    const int n0 = blockIdx.x * 128, o0 = blockIdx.y * 128;

    int srow[4], sslot[4];
#pragma unroll
    for (int p = 0; p < 4; ++p) {
        int item = tid + p * 256;
        srow[p] = item >> 3;
        sslot[p] = (item & 7) ^ (srow[p] & 7);
    }
    int aoff[2][4], boff[2][4];
#pragma unroll
    for (int ks = 0; ks < 2; ++ks)
#pragma unroll
        for (int f = 0; f < 4; ++f) {
            int ar = wm * 64 + f * 16 + lr;
            int br = wn * 64 + f * 16 + lr;
            aoff[ks][f] = ar * 64 + (((ks * 4 + lg) ^ (ar & 7)) * 8);
            boff[ks][f] = br * 64 + (((ks * 4 + lg) ^ (br & 7)) * 8);
        }

    f32x4 acc[4][4] = {};

#define STG1(buf, kt)                                                           \
    do {                                                                        \
        _Pragma("unroll")                                                       \
        for (int p = 0; p < 4; ++p) {                                           \
            GLL(A + (size_t)(n0 + srow[p]) * K + (kt) * 64 + sslot[p] * 8,      \
                &Al[buf][(tid + p * 256) * 8]);                                 \
            GLL(W + (size_t)(o0 + srow[p]) * K + (kt) * 64 + sslot[p] * 8,      \
                &Bl[buf][(tid + p * 256) * 8]);                                 \
        }                                                                       \
    } while (0)

    STG1(0, 0);
    STG1(1, 1);
    for (int t = 0; t < NT; ++t) {
        const int cur = t & 1;
        asm volatile("s_waitcnt vmcnt(8)" ::: "memory");
        __builtin_amdgcn_s_barrier();
        __builtin_amdgcn_sched_barrier(0);
        __builtin_amdgcn_s_setprio(1);
#pragma unroll
        for (int ks = 0; ks < 2; ++ks) {
            bf16x8 af[4], bfr[4];
#pragma unroll
            for (int f = 0; f < 4; ++f) af[f] = *(const bf16x8*)&Al[cur][aoff[ks][f]];
#pragma unroll
            for (int f = 0; f < 4; ++f) bfr[f] = *(const bf16x8*)&Bl[cur][boff[ks][f]];
#pragma unroll
            for (int fm = 0; fm < 4; ++fm)
#pragma unroll
                for (int fn = 0; fn < 4; ++fn)
                    acc[fm][fn] = __builtin_amdgcn_mfma_f32_16x16x32_bf16(
                        af[fm], bfr[fn], acc[fm][fn], 0, 0, 0);
        }
        __builtin_amdgcn_s_setprio(0);
        asm volatile("s_waitcnt lgkmcnt(0)" ::: "memory");
        __builtin_amdgcn_s_barrier();
        __builtin_amdgcn_sched_barrier(0);
        const int kn = (t + 2 < NT) ? t + 2 : NT - 1;
        STG1(cur, kn);
    }
#undef STG1
#pragma unroll
    for (int fm = 0; fm < 4; ++fm) {
#pragma unroll
        for (int fn = 0; fn < 4; ++fn) {
            int col = o0 + wn * 64 + fn * 16 + lr;
#pragma unroll
            for (int r = 0; r < 4; ++r) {
                int row = n0 + wm * 64 + fm * 16 + lg * 4 + r;
                float v = acc[fm][fn][r];
                H[(size_t)row * D_HID + col] = 0.5f * v * (1.0f + erff(v * 0.70710678118f));
            }
        }
    }
}

// ---------------- GEMM2: P[z] = expand(h) @ W2^T, B in registers ----------------
// BM=64, BN=256, BK=64, split-K=8. A (features) in 16KB dbuf LDS; B-frags are
// coalesced 1KB/wave register loads from W2f. 2 raw barriers/tile, lgkm only.
__global__ __launch_bounds__(256, 3)
void kan_gemm2(const float* __restrict__ H,
               const __hip_bfloat16* __restrict__ W2f,
               float* __restrict__ P) {
    constexpr int OUT = D_IN, KD = D_HID * 8;   // 8192
    constexpr int NTT = KD / 64;                // 128 k-tiles
    __shared__ __hip_bfloat16 Al[2][64 * 64];   // 16KB (reused as 64x64 f32 in epi)

    const int tid = threadIdx.x;
    const int wid = tid >> 6, lane = tid & 63;
    const int lr = lane & 15, lg = lane >> 4;
    const int n0 = blockIdx.x * 64;

    const int per = NTT / 8;                    // 16 tiles (even)
    const int ks0 = blockIdx.z * per, ks1 = ks0 + per;

    // A features: rows ar0, ar0+32; h-col-in-tile = tid&7
    const int ar0 = tid >> 3, ac = tid & 7;
    const float* hp0 = H + (size_t)(n0 + ar0) * D_HID + ac;
    const float* hp1 = H + (size_t)(n0 + ar0 + 32) * D_HID + ac;
    const int aw0 = ar0 * 64 + ((ac ^ (ar0 & 7)) * 8);
    const int aw1 = (ar0 + 32) * 64 + ((ac ^ ((ar0 + 32) & 7)) * 8);

    // B lane offsets (tile-invariant): elem (chunk*256+col)*32 + lg*8
    int bcol[4];
#pragma unroll
    for (int f = 0; f < 4; ++f)
        bcol[f] = (wid * 64 + f * 16 + lr) * 32 + lg * 8;

    int aoff[2][4];
#pragma unroll
    for (int ks = 0; ks < 2; ++ks)
#pragma unroll
        for (int f = 0; f < 4; ++f) {
            int ar = f * 16 + lr;
            aoff[ks][f] = ar * 64 + (((ks * 4 + lg) ^ (ar & 7)) * 8);
        }

    f32x4 acc[4][4] = {};

#define FEAT(buf, h0, h1)                                                       \
    do {                                                                        \
        float ff[8]; __hip_bfloat16 fb[8];                                      \
        kan_features(h0, ff); features_to_bf16(ff, fb);                         \
        *(bf16x8*)&Al[buf][aw0] = *(bf16x8*)fb;                                 \
        kan_features(h1, ff); features_to_bf16(ff, fb);                         \
        *(bf16x8*)&Al[buf][aw1] = *(bf16x8*)fb;                                 \
    } while (0)

    // SUB(T, b, nb): one k-tile. B loads first (latency hides under features).
#define SUB(T, b, nb, DO_STAGE)                                                 \
    do {                                                                        \
        bf16x8 bw[2][4];                                                        \
        _Pragma("unroll")                                                       \
        for (int ks = 0; ks < 2; ++ks)                                          \
            _Pragma("unroll")                                                   \
            for (int f = 0; f < 4; ++f)                                         \
                bw[ks][f] = *(const bf16x8*)&W2f[(size_t)((T) * 2 + ks) * 8192  \
                                                 + bcol[f]];                    \
        if (DO_STAGE) {                                                         \
            FEAT(nb, hA, hB);                                                   \
            int hn = ((T) + 2 < ks1) ? (T) + 2 : ks1 - 1;                       \
            hA = hp0[(size_t)hn * 8];                                           \
            hB = hp1[(size_t)hn * 8];                                           \
        }                                                                       \
        asm volatile("s_waitcnt lgkmcnt(0)" ::: "memory");                      \
        __builtin_amdgcn_sched_barrier(0);                                      \
        __builtin_amdgcn_s_barrier();                                           \
        __builtin_amdgcn_s_setprio(1);                                          \
        _Pragma("unroll")                                                       \
        for (int ks = 0; ks < 2; ++ks) {                                        \
            bf16x8 af[4];                                                       \
            _Pragma("unroll")                                                   \
            for (int f = 0; f < 4; ++f)                                         \
                af[f] = *(const bf16x8*)&Al[b][aoff[ks][f]];                    \
            _Pragma("unroll")                                                   \
            for (int fm = 0; fm < 4; ++fm)                                      \
                _Pragma("unroll")                                               \
                for (int fn = 0; fn < 4; ++fn)                                  \
                    acc[fm][fn] = __builtin_amdgcn_mfma_f32_16x16x32_bf16(      \
                        af[fm], bw[ks][fn], acc[fm][fn], 0, 0, 0);              \
        }                                                                       \
        __builtin_amdgcn_s_setprio(0);                                          \
        __builtin_amdgcn_s_barrier();                                           \
    } while (0)

    // prologue: stage tile ks0 into buf0; preload h for ks0+1
    {
        float h0 = hp0[(size_t)ks0 * 8];
        float h1 = hp1[(size_t)ks0 * 8];
        FEAT(0, h0, h1);
    }
    float hA = hp0[(size_t)(ks0 + 1) * 8];
    float hB = hp1[(size_t)(ks0 + 1) * 8];

    for (int t = ks0; t < ks1; t += 2) {
        SUB(t, 0, 1, 1);                         // even: stage t+1 (always valid)
        SUB(t + 1, 1, 0, (t + 2 < ks1));         // odd: stage t+2 unless last
    }
#undef SUB
#undef FEAT

    // ---- epilogue: 4 quarter-passes through 16KB LDS, coalesced f32x4 stores ----
    float* Pl = (float*)Al;                      // 64 x 64 f32 = 16KB
    const size_t zoff = (size_t)blockIdx.z * TOKENS * OUT;
#pragma unroll
    for (int q = 0; q < 4; ++q) {
        __syncthreads();
        if (wid == q) {
#pragma unroll
            for (int fm = 0; fm < 4; ++fm)
#pragma unroll
                for (int fn = 0; fn < 4; ++fn)
#pragma unroll
                    for (int r = 0; r < 4; ++r)
                        Pl[(fm * 16 + lg * 4 + r) * 64 + fn * 16 + lr] = acc[fm][fn][r];
        }
        __syncthreads();
#pragma unroll
        for (int p = 0; p < 4; ++p) {
            int v = tid + p * 256;               // 0..1023
            int row = v >> 4, cv = (v & 15) * 4;
            *(f32x4*)&P[zoff + (size_t)(n0 + row) * OUT + q * 64 + cv] =
                *(const f32x4*)&Pl[row * 64 + cv];
        }
    }
}

// ---------------- reduce 8 partial slices -> out ----------------
__global__ void reduce_split(const float* __restrict__ P, float* __restrict__ out,
                             int nvec) {
    int i = blockIdx.x * 256 + threadIdx.x;
    if (i >= nvec) return;
    const f32x4* Pv = (const f32x4*)P;
    f32x4 s = Pv[i];
#pragma unroll
    for (int z = 1; z < 8; ++z) s += Pv[(size_t)z * nvec + i];
    ((f32x4*)out)[i] = s;
}

extern "C" void kernel_launch(void* const* d_in, const int* in_sizes, int n_in,
                              void* d_out, int out_size, void* d_ws, size_t ws_size,
                              hipStream_t stream) {
    const float* x   = (const float*)d_in[0];
    const float* bw1 = (const float*)d_in[1];
    const float* sw1 = (const float*)d_in[2];
    const float* sc1 = (const float*)d_in[3];
    const float* bw2 = (const float*)d_in[4];
    const float* sw2 = (const float*)d_in[5];
    const float* sc2 = (const float*)d_in[6];
    float* out = (float*)d_out;

    char* ws = (char*)d_ws;
    __hip_bfloat16* W1  = (__hip_bfloat16*)ws;                   // 4MB
    __hip_bfloat16* W2f = (__hip_bfloat16*)(ws + (4ull << 20));  // 4MB fragment-major
    __hip_bfloat16* F1  = (__hip_bfloat16*)(ws + (8ull << 20));  // 32MB
    float*          Hb  = (float*)(ws + (40ull << 20));          // 32MB
    float*          Pp  = (float*)(ws + (72ull << 20));          // 64MB

    if (ws_size < (136ull << 20)) return;

    // fused: expand_x (8192 blocks) + prep W1 (1024) + prep W2f (1024)
    init_fused<<<10240, 256, 0, stream>>>(x, F1, bw1, sw1, sc1, W1, bw2, sw2, sc2, W2f);

    // GEMM1: (8192 x 2048) @ (1024 x 2048)^T + GELU -> Hb
    kan_gemm1<<<dim3(TOKENS / 128, D_HID / 128), 256, 0, stream>>>(F1, W1, Hb);

    // GEMM2: expand(Hb) @ W2f -> 8 partial slices
    kan_gemm2<<<dim3(TOKENS / 64, 1, 8), 256, 0, stream>>>(Hb, W2f, Pp);

    // Reduce partials -> out
    const int nvec = TOKENS * D_IN / 4;  // 524288
    reduce_split<<<(nvec + 255) / 256, 256, 0, stream>>>(Pp, out, nvec);
}